// Round 2
// baseline (2879.608 us; speedup 1.0000x reference)
//
#include <hip/hip_runtime.h>

#define N_NODES 100000
#define N_EDGES 1600000
#define DIM 128
#define LEAKY 0.01f
#define RS_STRIDE 132   // 128 + 4 pad: float4-aligned, spreads LDS banks
#define WS_STRIDE 132

// ---------------------------------------------------------------------------
// Phase 1: scatter-add messages. 32 threads per edge, float4 per thread.
// agg[dst] += x[src] * attr[e]
// NOTE: edge_index arrives as int32 (harness converts integer inputs).
// ---------------------------------------------------------------------------
__global__ __launch_bounds__(256) void scatter_kernel(
    const float* __restrict__ x,
    const int* __restrict__ ei,     // [2, N_EDGES] int32
    const float* __restrict__ attr,
    float* __restrict__ agg) {
  int gid = blockIdx.x * blockDim.x + threadIdx.x;
  int e = gid >> 5;          // edge id
  int f = (gid & 31) * 4;    // feature offset
  if (e >= N_EDGES) return;
  int s = ei[e];
  int d = ei[N_EDGES + e];
  float a = attr[e];
  const float4 xv = *(const float4*)(x + (size_t)s * DIM + f);
  float* dp = agg + (size_t)d * DIM + f;
  atomicAdd(dp + 0, xv.x * a);
  atomicAdd(dp + 1, xv.y * a);
  atomicAdd(dp + 2, xv.z * a);
  atomicAdd(dp + 3, xv.w * a);
}

// ---------------------------------------------------------------------------
// Phase 2: out = LeakyReLU(agg @ W^T + b), in-place-safe (agg may == out).
// Block: 256 threads, 32 rows. Thread = 4 rows x 4 cols.
// Rows staged in LDS behind a barrier before any writeback -> in-place safe.
// W^T staged in LDS in two K-halves (33 KB each) to stay under 64 KB static.
// ---------------------------------------------------------------------------
__global__ __launch_bounds__(256, 2) void linear_kernel(
    const float* __restrict__ agg,
    const float* __restrict__ W,
    const float* __restrict__ bias,
    float* __restrict__ out) {
  __shared__ float Rs[32 * RS_STRIDE];  // 16.9 KB: this block's 32 rows
  __shared__ float Ws[64 * WS_STRIDE];  // 33.8 KB: W^T, one 64-wide K-half

  const int tid = threadIdx.x;
  const int c = (tid & 31) * 4;       // output col base
  const int rg = tid >> 5;            // 0..7 row group
  const size_t rowBase = (size_t)blockIdx.x * 32;

  // Stage this block's 32 rows into LDS (coalesced: 16 KB contiguous).
  {
    const int lr = tid >> 3;          // 0..31
    const int col = (tid & 7) * 16;   // 0,16,...,112
    const float4* src = (const float4*)(agg + (rowBase + lr) * DIM + col);
#pragma unroll
    for (int j = 0; j < 4; ++j) {
      *(float4*)(Rs + lr * RS_STRIDE + col + j * 4) = src[j];
    }
  }

  const float4 bv = *(const float4*)(bias + c);
  float4 acc0 = bv, acc1 = bv, acc2 = bv, acc3 = bv;

  for (int half = 0; half < 2; ++half) {
    __syncthreads();  // Rs ready (iter 0) / prior Ws reads done (iter 1)
    // Stage Ws[k][o] = W[o][half*64+k]; lanes write consecutive o -> no conflict
    {
      const int k0 = tid >> 7;        // 0..1
      const int o = tid & 127;
#pragma unroll
      for (int kk = k0; kk < 64; kk += 2) {
        Ws[kk * WS_STRIDE + o] = W[o * DIM + half * 64 + kk];
      }
    }
    __syncthreads();

    const float* rs0 = Rs + (rg * 4 + 0) * RS_STRIDE + half * 64;
    const float* rs1 = Rs + (rg * 4 + 1) * RS_STRIDE + half * 64;
    const float* rs2 = Rs + (rg * 4 + 2) * RS_STRIDE + half * 64;
    const float* rs3 = Rs + (rg * 4 + 3) * RS_STRIDE + half * 64;

#pragma unroll 8
    for (int k4 = 0; k4 < 16; ++k4) {
      const float4 v0 = *(const float4*)(rs0 + k4 * 4);
      const float4 v1 = *(const float4*)(rs1 + k4 * 4);
      const float4 v2 = *(const float4*)(rs2 + k4 * 4);
      const float4 v3 = *(const float4*)(rs3 + k4 * 4);
      const float4 w0 = *(const float4*)(Ws + (k4 * 4 + 0) * WS_STRIDE + c);
      const float4 w1 = *(const float4*)(Ws + (k4 * 4 + 1) * WS_STRIDE + c);
      const float4 w2 = *(const float4*)(Ws + (k4 * 4 + 2) * WS_STRIDE + c);
      const float4 w3 = *(const float4*)(Ws + (k4 * 4 + 3) * WS_STRIDE + c);

#define FMA4(acc, v)                                               \
      acc.x += v.x * w0.x + v.y * w1.x + v.z * w2.x + v.w * w3.x;  \
      acc.y += v.x * w0.y + v.y * w1.y + v.z * w2.y + v.w * w3.y;  \
      acc.z += v.x * w0.z + v.y * w1.z + v.z * w2.z + v.w * w3.z;  \
      acc.w += v.x * w0.w + v.y * w1.w + v.z * w2.w + v.w * w3.w;
      FMA4(acc0, v0)
      FMA4(acc1, v1)
      FMA4(acc2, v2)
      FMA4(acc3, v3)
#undef FMA4
    }
  }

#define LEAKY4(acc)                                   \
  acc.x = acc.x >= 0.f ? acc.x : acc.x * LEAKY;       \
  acc.y = acc.y >= 0.f ? acc.y : acc.y * LEAKY;       \
  acc.z = acc.z >= 0.f ? acc.z : acc.z * LEAKY;       \
  acc.w = acc.w >= 0.f ? acc.w : acc.w * LEAKY;
  LEAKY4(acc0) LEAKY4(acc1) LEAKY4(acc2) LEAKY4(acc3)
#undef LEAKY4

  const int row0 = (int)rowBase + rg * 4;
  *(float4*)(out + (size_t)(row0 + 0) * DIM + c) = acc0;
  *(float4*)(out + (size_t)(row0 + 1) * DIM + c) = acc1;
  *(float4*)(out + (size_t)(row0 + 2) * DIM + c) = acc2;
  *(float4*)(out + (size_t)(row0 + 3) * DIM + c) = acc3;
}

extern "C" void kernel_launch(void* const* d_in, const int* in_sizes, int n_in,
                              void* d_out, int out_size, void* d_ws, size_t ws_size,
                              hipStream_t stream) {
  const float* x = (const float*)d_in[0];
  const int* ei = (const int*)d_in[1];     // int32 (harness converts int64)
  const float* attr = (const float*)d_in[2];
  const float* W = (const float*)d_in[3];
  const float* b = (const float*)d_in[4];
  float* out = (float*)d_out;

  const size_t aggBytes = (size_t)N_NODES * DIM * sizeof(float);
  // Use workspace for the aggregation buffer only if it's big enough;
  // otherwise aggregate in-place into d_out (linear_kernel is in-place safe).
  float* agg = (ws_size >= aggBytes) ? (float*)d_ws : out;

  hipMemsetAsync(agg, 0, aggBytes, stream);

  // 1.6M edges * 32 threads / 256 = 200000 blocks
  scatter_kernel<<<(N_EDGES * 32) / 256, 256, 0, stream>>>(x, ei, attr, agg);

  linear_kernel<<<N_NODES / 32, 256, 0, stream>>>(agg, W, b, out);
}

// Round 3
// 771.044 us; speedup vs baseline: 3.7347x; 3.7347x over previous
//
#include <hip/hip_runtime.h>

#define N_NODES 100000
#define N_EDGES 1600000
#define DIM 128
#define LEAKY 0.01f
#define RS_STRIDE 132
#define WS_STRIDE 132

// ---------------------------------------------------------------------------
// CSR build phase
// ---------------------------------------------------------------------------
__global__ __launch_bounds__(256) void hist_kernel(
    const int* __restrict__ ei, int* __restrict__ counts) {
  int e = blockIdx.x * blockDim.x + threadIdx.x;
  if (e >= N_EDGES) return;
  atomicAdd(counts + ei[N_EDGES + e], 1);
}

// Single block, 1024 threads. Exclusive scan of counts[0..N) into
// row_ptr[0..N] (row_ptr[N] = E) and a second copy into cursor[].
__global__ __launch_bounds__(1024) void scan_kernel(
    const int* __restrict__ counts, int* __restrict__ row_ptr,
    int* __restrict__ cursor) {
  __shared__ int sums[1024];
  const int PER = (N_NODES + 1023) / 1024;  // 98
  const int t = threadIdx.x;
  const int base = t * PER;

  int local = 0;
  for (int i = 0; i < PER; ++i) {
    int idx = base + i;
    if (idx < N_NODES) local += counts[idx];
  }
  sums[t] = local;
  __syncthreads();
  // inclusive Hillis-Steele
  for (int off = 1; off < 1024; off <<= 1) {
    int v = (t >= off) ? sums[t - off] : 0;
    __syncthreads();
    sums[t] += v;
    __syncthreads();
  }
  int run = (t > 0) ? sums[t - 1] : 0;  // exclusive offset
  for (int i = 0; i < PER; ++i) {
    int idx = base + i;
    if (idx < N_NODES) {
      row_ptr[idx] = run;
      cursor[idx] = run;
      run += counts[idx];
    }
  }
  if (t == 1023) row_ptr[N_NODES] = sums[1023];  // == N_EDGES
}

__global__ __launch_bounds__(256) void fill_kernel(
    const int* __restrict__ ei, const float* __restrict__ attr,
    int* __restrict__ cursor, int2* __restrict__ csr) {
  int e = blockIdx.x * blockDim.x + threadIdx.x;
  if (e >= N_EDGES) return;
  int s = ei[e];
  int d = ei[N_EDGES + e];
  int pos = atomicAdd(cursor + d, 1);
  csr[pos] = make_int2(s, __float_as_int(attr[e]));
}

// ---------------------------------------------------------------------------
// Gather aggregation: one wave (64 lanes) per node, float2 per lane.
// agg[n] = sum_{e in row(n)} x[src_e] * attr_e   -> written to out[]
// ---------------------------------------------------------------------------
__global__ __launch_bounds__(256) void gather_kernel(
    const float* __restrict__ x, const int* __restrict__ row_ptr,
    const int2* __restrict__ csr, float* __restrict__ out) {
  const int node = blockIdx.x * 4 + (threadIdx.x >> 6);
  const int lane = threadIdx.x & 63;
  if (node >= N_NODES) return;

  const int beg = row_ptr[node];
  const int end = row_ptr[node + 1];

  float2 acc = make_float2(0.f, 0.f);
  int e = beg;
  for (; e + 1 < end; e += 2) {
    int2 e0 = csr[e];
    int2 e1 = csr[e + 1];
    float a0 = __int_as_float(e0.y);
    float a1 = __int_as_float(e1.y);
    float2 v0 = *(const float2*)(x + (size_t)e0.x * DIM + lane * 2);
    float2 v1 = *(const float2*)(x + (size_t)e1.x * DIM + lane * 2);
    acc.x += v0.x * a0;
    acc.y += v0.y * a0;
    acc.x += v1.x * a1;
    acc.y += v1.y * a1;
  }
  if (e < end) {
    int2 e0 = csr[e];
    float a0 = __int_as_float(e0.y);
    float2 v0 = *(const float2*)(x + (size_t)e0.x * DIM + lane * 2);
    acc.x += v0.x * a0;
    acc.y += v0.y * a0;
  }
  *(float2*)(out + (size_t)node * DIM + lane * 2) = acc;
}

// ---------------------------------------------------------------------------
// Fallback scatter (atomic) path, used only if ws_size is too small.
// ---------------------------------------------------------------------------
__global__ __launch_bounds__(256) void scatter_kernel(
    const float* __restrict__ x, const int* __restrict__ ei,
    const float* __restrict__ attr, float* __restrict__ agg) {
  int gid = blockIdx.x * blockDim.x + threadIdx.x;
  int e = gid >> 5;
  int f = (gid & 31) * 4;
  if (e >= N_EDGES) return;
  int s = ei[e];
  int d = ei[N_EDGES + e];
  float a = attr[e];
  const float4 xv = *(const float4*)(x + (size_t)s * DIM + f);
  float* dp = agg + (size_t)d * DIM + f;
  atomicAdd(dp + 0, xv.x * a);
  atomicAdd(dp + 1, xv.y * a);
  atomicAdd(dp + 2, xv.z * a);
  atomicAdd(dp + 3, xv.w * a);
}

// ---------------------------------------------------------------------------
// out = LeakyReLU(agg @ W^T + b), in-place safe (agg may == out).
// ---------------------------------------------------------------------------
__global__ __launch_bounds__(256, 2) void linear_kernel(
    const float* __restrict__ agg, const float* __restrict__ W,
    const float* __restrict__ bias, float* __restrict__ out) {
  __shared__ float Rs[32 * RS_STRIDE];
  __shared__ float Ws[64 * WS_STRIDE];

  const int tid = threadIdx.x;
  const int c = (tid & 31) * 4;
  const int rg = tid >> 5;
  const size_t rowBase = (size_t)blockIdx.x * 32;

  {
    const int lr = tid >> 3;
    const int col = (tid & 7) * 16;
    const float4* src = (const float4*)(agg + (rowBase + lr) * DIM + col);
#pragma unroll
    for (int j = 0; j < 4; ++j) {
      *(float4*)(Rs + lr * RS_STRIDE + col + j * 4) = src[j];
    }
  }

  const float4 bv = *(const float4*)(bias + c);
  float4 acc0 = bv, acc1 = bv, acc2 = bv, acc3 = bv;

  for (int half = 0; half < 2; ++half) {
    __syncthreads();
    {
      const int k0 = tid >> 7;
      const int o = tid & 127;
#pragma unroll
      for (int kk = k0; kk < 64; kk += 2) {
        Ws[kk * WS_STRIDE + o] = W[o * DIM + half * 64 + kk];
      }
    }
    __syncthreads();

    const float* rs0 = Rs + (rg * 4 + 0) * RS_STRIDE + half * 64;
    const float* rs1 = Rs + (rg * 4 + 1) * RS_STRIDE + half * 64;
    const float* rs2 = Rs + (rg * 4 + 2) * RS_STRIDE + half * 64;
    const float* rs3 = Rs + (rg * 4 + 3) * RS_STRIDE + half * 64;

#pragma unroll 8
    for (int k4 = 0; k4 < 16; ++k4) {
      const float4 v0 = *(const float4*)(rs0 + k4 * 4);
      const float4 v1 = *(const float4*)(rs1 + k4 * 4);
      const float4 v2 = *(const float4*)(rs2 + k4 * 4);
      const float4 v3 = *(const float4*)(rs3 + k4 * 4);
      const float4 w0 = *(const float4*)(Ws + (k4 * 4 + 0) * WS_STRIDE + c);
      const float4 w1 = *(const float4*)(Ws + (k4 * 4 + 1) * WS_STRIDE + c);
      const float4 w2 = *(const float4*)(Ws + (k4 * 4 + 2) * WS_STRIDE + c);
      const float4 w3 = *(const float4*)(Ws + (k4 * 4 + 3) * WS_STRIDE + c);

#define FMA4(acc, v)                                               \
      acc.x += v.x * w0.x + v.y * w1.x + v.z * w2.x + v.w * w3.x;  \
      acc.y += v.x * w0.y + v.y * w1.y + v.z * w2.y + v.w * w3.y;  \
      acc.z += v.x * w0.z + v.y * w1.z + v.z * w2.z + v.w * w3.z;  \
      acc.w += v.x * w0.w + v.y * w1.w + v.z * w2.w + v.w * w3.w;
      FMA4(acc0, v0)
      FMA4(acc1, v1)
      FMA4(acc2, v2)
      FMA4(acc3, v3)
#undef FMA4
    }
  }

#define LEAKY4(acc)                                   \
  acc.x = acc.x >= 0.f ? acc.x : acc.x * LEAKY;       \
  acc.y = acc.y >= 0.f ? acc.y : acc.y * LEAKY;       \
  acc.z = acc.z >= 0.f ? acc.z : acc.z * LEAKY;       \
  acc.w = acc.w >= 0.f ? acc.w : acc.w * LEAKY;
  LEAKY4(acc0) LEAKY4(acc1) LEAKY4(acc2) LEAKY4(acc3)
#undef LEAKY4

  const int row0 = (int)rowBase + rg * 4;
  *(float4*)(out + (size_t)(row0 + 0) * DIM + c) = acc0;
  *(float4*)(out + (size_t)(row0 + 1) * DIM + c) = acc1;
  *(float4*)(out + (size_t)(row0 + 2) * DIM + c) = acc2;
  *(float4*)(out + (size_t)(row0 + 3) * DIM + c) = acc3;
}

extern "C" void kernel_launch(void* const* d_in, const int* in_sizes, int n_in,
                              void* d_out, int out_size, void* d_ws, size_t ws_size,
                              hipStream_t stream) {
  const float* x = (const float*)d_in[0];
  const int* ei = (const int*)d_in[1];  // int32 (harness converts int64)
  const float* attr = (const float*)d_in[2];
  const float* W = (const float*)d_in[3];
  const float* b = (const float*)d_in[4];
  float* out = (float*)d_out;

  // Workspace layout (all 256B-aligned offsets)
  const size_t offCounts = 0;                       // N ints
  const size_t offRowPtr = 400128;                  // N+1 ints
  const size_t offCursor = 800256;                  // N ints
  const size_t offCsr = 1200384;                    // E int2 (8B each)
  const size_t wsNeeded = offCsr + (size_t)N_EDGES * 8;  // ~14.0 MB

  if (ws_size >= wsNeeded) {
    char* ws = (char*)d_ws;
    int* counts = (int*)(ws + offCounts);
    int* row_ptr = (int*)(ws + offRowPtr);
    int* cursor = (int*)(ws + offCursor);
    int2* csr = (int2*)(ws + offCsr);

    hipMemsetAsync(counts, 0, (size_t)N_NODES * sizeof(int), stream);
    hist_kernel<<<(N_EDGES + 255) / 256, 256, 0, stream>>>(ei, counts);
    scan_kernel<<<1, 1024, 0, stream>>>(counts, row_ptr, cursor);
    fill_kernel<<<(N_EDGES + 255) / 256, 256, 0, stream>>>(ei, attr, cursor, csr);
    gather_kernel<<<(N_NODES + 3) / 4, 256, 0, stream>>>(x, row_ptr, csr, out);
  } else {
    // Fallback: atomic scatter directly into out
    hipMemsetAsync(out, 0, (size_t)N_NODES * DIM * sizeof(float), stream);
    scatter_kernel<<<(N_EDGES * 32) / 256, 256, 0, stream>>>(x, ei, attr, out);
  }

  linear_kernel<<<N_NODES / 32, 256, 0, stream>>>(out, W, b, out);
}

// Round 4
// 512.783 us; speedup vs baseline: 5.6156x; 1.5036x over previous
//
#include <hip/hip_runtime.h>

#define N_NODES 100000
#define N_EDGES 1600000
#define DIM 128
#define LEAKY 0.01f
#define RS_STRIDE 132
#define WS_STRIDE 132
#define SCAN_BLK 391  // ceil(100000/256)

// ---------------------------------------------------------------------------
// CSR build phase
// ---------------------------------------------------------------------------
__global__ __launch_bounds__(256) void hist_kernel(
    const int* __restrict__ ei, int* __restrict__ counts) {
  int e = blockIdx.x * blockDim.x + threadIdx.x;
  if (e >= N_EDGES) return;
  atomicAdd(counts + ei[N_EDGES + e], 1);
}

// Hierarchical scan, step 1: per-256-chunk sums.
__global__ __launch_bounds__(256) void partial_kernel(
    const int* __restrict__ counts, int* __restrict__ blockSums) {
  __shared__ int s[256];
  const int t = threadIdx.x;
  const int idx = blockIdx.x * 256 + t;
  s[t] = (idx < N_NODES) ? counts[idx] : 0;
  __syncthreads();
  for (int off = 128; off > 0; off >>= 1) {
    if (t < off) s[t] += s[t + off];
    __syncthreads();
  }
  if (t == 0) blockSums[blockIdx.x] = s[0];
}

// Step 2: single small block scans the 391 block sums (exclusive).
__global__ __launch_bounds__(512) void scan_blk_kernel(
    const int* __restrict__ blockSums, int* __restrict__ blockOff,
    int* __restrict__ row_ptr) {
  __shared__ int s[512];
  const int t = threadIdx.x;
  int v = (t < SCAN_BLK) ? blockSums[t] : 0;
  s[t] = v;
  __syncthreads();
  for (int off = 1; off < 512; off <<= 1) {
    int u = (t >= off) ? s[t - off] : 0;
    __syncthreads();
    s[t] += u;
    __syncthreads();
  }
  if (t < SCAN_BLK) blockOff[t] = s[t] - v;  // exclusive
  if (t == 511) row_ptr[N_NODES] = s[511];   // == N_EDGES
}

// Step 3: per-chunk exclusive scan + block offset -> row_ptr, cursor.
__global__ __launch_bounds__(256) void scan_fin_kernel(
    const int* __restrict__ counts, const int* __restrict__ blockOff,
    int* __restrict__ row_ptr, int* __restrict__ cursor) {
  __shared__ int s[256];
  const int t = threadIdx.x;
  const int idx = blockIdx.x * 256 + t;
  const int v = (idx < N_NODES) ? counts[idx] : 0;
  s[t] = v;
  __syncthreads();
  for (int off = 1; off < 256; off <<= 1) {
    int u = (t >= off) ? s[t - off] : 0;
    __syncthreads();
    s[t] += u;
    __syncthreads();
  }
  if (idx < N_NODES) {
    int excl = s[t] - v + blockOff[blockIdx.x];
    row_ptr[idx] = excl;
    cursor[idx] = excl;
  }
}

__global__ __launch_bounds__(256) void fill_kernel(
    const int* __restrict__ ei, const float* __restrict__ attr,
    int* __restrict__ cursor, int2* __restrict__ csr) {
  int e = blockIdx.x * blockDim.x + threadIdx.x;
  if (e >= N_EDGES) return;
  int s = ei[e];
  int d = ei[N_EDGES + e];
  int pos = atomicAdd(cursor + d, 1);
  csr[pos] = make_int2(s, __float_as_int(attr[e]));
}

// ---------------------------------------------------------------------------
// Gather aggregation: one wave (64 lanes) per node, float2 per lane.
// ---------------------------------------------------------------------------
__global__ __launch_bounds__(256) void gather_kernel(
    const float* __restrict__ x, const int* __restrict__ row_ptr,
    const int2* __restrict__ csr, float* __restrict__ out) {
  const int node = blockIdx.x * 4 + (threadIdx.x >> 6);
  const int lane = threadIdx.x & 63;
  if (node >= N_NODES) return;

  const int beg = row_ptr[node];
  const int end = row_ptr[node + 1];

  float2 acc = make_float2(0.f, 0.f);
  int e = beg;
  for (; e + 3 < end; e += 4) {
    int2 e0 = csr[e];
    int2 e1 = csr[e + 1];
    int2 e2 = csr[e + 2];
    int2 e3 = csr[e + 3];
    float2 v0 = *(const float2*)(x + (size_t)e0.x * DIM + lane * 2);
    float2 v1 = *(const float2*)(x + (size_t)e1.x * DIM + lane * 2);
    float2 v2 = *(const float2*)(x + (size_t)e2.x * DIM + lane * 2);
    float2 v3 = *(const float2*)(x + (size_t)e3.x * DIM + lane * 2);
    float a0 = __int_as_float(e0.y), a1 = __int_as_float(e1.y);
    float a2 = __int_as_float(e2.y), a3 = __int_as_float(e3.y);
    acc.x += v0.x * a0; acc.y += v0.y * a0;
    acc.x += v1.x * a1; acc.y += v1.y * a1;
    acc.x += v2.x * a2; acc.y += v2.y * a2;
    acc.x += v3.x * a3; acc.y += v3.y * a3;
  }
  for (; e < end; ++e) {
    int2 e0 = csr[e];
    float a0 = __int_as_float(e0.y);
    float2 v0 = *(const float2*)(x + (size_t)e0.x * DIM + lane * 2);
    acc.x += v0.x * a0; acc.y += v0.y * a0;
  }
  *(float2*)(out + (size_t)node * DIM + lane * 2) = acc;
}

// ---------------------------------------------------------------------------
// Fallback scatter (atomic) path, used only if ws_size is too small.
// ---------------------------------------------------------------------------
__global__ __launch_bounds__(256) void scatter_kernel(
    const float* __restrict__ x, const int* __restrict__ ei,
    const float* __restrict__ attr, float* __restrict__ agg) {
  int gid = blockIdx.x * blockDim.x + threadIdx.x;
  int e = gid >> 5;
  int f = (gid & 31) * 4;
  if (e >= N_EDGES) return;
  int s = ei[e];
  int d = ei[N_EDGES + e];
  float a = attr[e];
  const float4 xv = *(const float4*)(x + (size_t)s * DIM + f);
  float* dp = agg + (size_t)d * DIM + f;
  atomicAdd(dp + 0, xv.x * a);
  atomicAdd(dp + 1, xv.y * a);
  atomicAdd(dp + 2, xv.z * a);
  atomicAdd(dp + 3, xv.w * a);
}

// ---------------------------------------------------------------------------
// out = LeakyReLU(agg @ W^T + b), in-place safe (agg may == out).
// ---------------------------------------------------------------------------
__global__ __launch_bounds__(256, 2) void linear_kernel(
    const float* __restrict__ agg, const float* __restrict__ W,
    const float* __restrict__ bias, float* __restrict__ out) {
  __shared__ float Rs[32 * RS_STRIDE];
  __shared__ float Ws[64 * WS_STRIDE];

  const int tid = threadIdx.x;
  const int c = (tid & 31) * 4;
  const int rg = tid >> 5;
  const size_t rowBase = (size_t)blockIdx.x * 32;

  {
    const int lr = tid >> 3;
    const int col = (tid & 7) * 16;
    const float4* src = (const float4*)(agg + (rowBase + lr) * DIM + col);
#pragma unroll
    for (int j = 0; j < 4; ++j) {
      *(float4*)(Rs + lr * RS_STRIDE + col + j * 4) = src[j];
    }
  }

  const float4 bv = *(const float4*)(bias + c);
  float4 acc0 = bv, acc1 = bv, acc2 = bv, acc3 = bv;

  for (int half = 0; half < 2; ++half) {
    __syncthreads();
    {
      const int k0 = tid >> 7;
      const int o = tid & 127;
#pragma unroll
      for (int kk = k0; kk < 64; kk += 2) {
        Ws[kk * WS_STRIDE + o] = W[o * DIM + half * 64 + kk];
      }
    }
    __syncthreads();

    const float* rs0 = Rs + (rg * 4 + 0) * RS_STRIDE + half * 64;
    const float* rs1 = Rs + (rg * 4 + 1) * RS_STRIDE + half * 64;
    const float* rs2 = Rs + (rg * 4 + 2) * RS_STRIDE + half * 64;
    const float* rs3 = Rs + (rg * 4 + 3) * RS_STRIDE + half * 64;

#pragma unroll 8
    for (int k4 = 0; k4 < 16; ++k4) {
      const float4 v0 = *(const float4*)(rs0 + k4 * 4);
      const float4 v1 = *(const float4*)(rs1 + k4 * 4);
      const float4 v2 = *(const float4*)(rs2 + k4 * 4);
      const float4 v3 = *(const float4*)(rs3 + k4 * 4);
      const float4 w0 = *(const float4*)(Ws + (k4 * 4 + 0) * WS_STRIDE + c);
      const float4 w1 = *(const float4*)(Ws + (k4 * 4 + 1) * WS_STRIDE + c);
      const float4 w2 = *(const float4*)(Ws + (k4 * 4 + 2) * WS_STRIDE + c);
      const float4 w3 = *(const float4*)(Ws + (k4 * 4 + 3) * WS_STRIDE + c);

#define FMA4(acc, v)                                               \
      acc.x += v.x * w0.x + v.y * w1.x + v.z * w2.x + v.w * w3.x;  \
      acc.y += v.x * w0.y + v.y * w1.y + v.z * w2.y + v.w * w3.y;  \
      acc.z += v.x * w0.z + v.y * w1.z + v.z * w2.z + v.w * w3.z;  \
      acc.w += v.x * w0.w + v.y * w1.w + v.z * w2.w + v.w * w3.w;
      FMA4(acc0, v0)
      FMA4(acc1, v1)
      FMA4(acc2, v2)
      FMA4(acc3, v3)
#undef FMA4
    }
  }

#define LEAKY4(acc)                                   \
  acc.x = acc.x >= 0.f ? acc.x : acc.x * LEAKY;       \
  acc.y = acc.y >= 0.f ? acc.y : acc.y * LEAKY;       \
  acc.z = acc.z >= 0.f ? acc.z : acc.z * LEAKY;       \
  acc.w = acc.w >= 0.f ? acc.w : acc.w * LEAKY;
  LEAKY4(acc0) LEAKY4(acc1) LEAKY4(acc2) LEAKY4(acc3)
#undef LEAKY4

  const int row0 = (int)rowBase + rg * 4;
  *(float4*)(out + (size_t)(row0 + 0) * DIM + c) = acc0;
  *(float4*)(out + (size_t)(row0 + 1) * DIM + c) = acc1;
  *(float4*)(out + (size_t)(row0 + 2) * DIM + c) = acc2;
  *(float4*)(out + (size_t)(row0 + 3) * DIM + c) = acc3;
}

extern "C" void kernel_launch(void* const* d_in, const int* in_sizes, int n_in,
                              void* d_out, int out_size, void* d_ws, size_t ws_size,
                              hipStream_t stream) {
  const float* x = (const float*)d_in[0];
  const int* ei = (const int*)d_in[1];  // int32 (harness converts int64)
  const float* attr = (const float*)d_in[2];
  const float* W = (const float*)d_in[3];
  const float* b = (const float*)d_in[4];
  float* out = (float*)d_out;

  // Workspace layout (256B-aligned offsets)
  const size_t offCounts = 0;                       // N ints
  const size_t offRowPtr = 400128;                  // N+1 ints
  const size_t offCursor = 800256;                  // N ints
  const size_t offCsr = 1200384;                    // E int2
  const size_t offBs = offCsr + (size_t)N_EDGES * 8;        // 391 ints
  const size_t offBo = offBs + 1792;                        // 391 ints
  const size_t wsNeeded = offBo + 1792;                     // ~14.0 MB

  if (ws_size >= wsNeeded) {
    char* ws = (char*)d_ws;
    int* counts = (int*)(ws + offCounts);
    int* row_ptr = (int*)(ws + offRowPtr);
    int* cursor = (int*)(ws + offCursor);
    int2* csr = (int2*)(ws + offCsr);
    int* blockSums = (int*)(ws + offBs);
    int* blockOff = (int*)(ws + offBo);

    hipMemsetAsync(counts, 0, (size_t)N_NODES * sizeof(int), stream);
    hist_kernel<<<(N_EDGES + 255) / 256, 256, 0, stream>>>(ei, counts);
    partial_kernel<<<SCAN_BLK, 256, 0, stream>>>(counts, blockSums);
    scan_blk_kernel<<<1, 512, 0, stream>>>(blockSums, blockOff, row_ptr);
    scan_fin_kernel<<<SCAN_BLK, 256, 0, stream>>>(counts, blockOff, row_ptr, cursor);
    fill_kernel<<<(N_EDGES + 255) / 256, 256, 0, stream>>>(ei, attr, cursor, csr);
    gather_kernel<<<(N_NODES + 3) / 4, 256, 0, stream>>>(x, row_ptr, csr, out);
  } else {
    hipMemsetAsync(out, 0, (size_t)N_NODES * DIM * sizeof(float), stream);
    scatter_kernel<<<(N_EDGES * 32) / 256, 256, 0, stream>>>(x, ei, attr, out);
  }

  linear_kernel<<<N_NODES / 32, 256, 0, stream>>>(out, W, b, out);
}

// Round 5
// 418.143 us; speedup vs baseline: 6.8867x; 1.2263x over previous
//
#include <hip/hip_runtime.h>

#define N_NODES 100000
#define N_EDGES 1600000
#define DIM 128
#define LEAKY 0.01f
#define RS_STRIDE 132
#define WS_STRIDE 132
#define SCAN_BLK 391  // ceil(100000/256)

typedef short bf16x8 __attribute__((ext_vector_type(8)));
typedef float f32x4 __attribute__((ext_vector_type(4)));

static __device__ __forceinline__ unsigned short f2bf(float f) {
  unsigned int u = __float_as_uint(f);
  u = (u + 0x7fffu + ((u >> 16) & 1u)) >> 16;  // RNE
  return (unsigned short)u;
}

// ---------------------------------------------------------------------------
// CSR build phase
// ---------------------------------------------------------------------------
__global__ __launch_bounds__(256) void hist_kernel(
    const int* __restrict__ ei, int* __restrict__ counts) {
  int e = blockIdx.x * blockDim.x + threadIdx.x;
  if (e >= N_EDGES) return;
  atomicAdd(counts + ei[N_EDGES + e], 1);
}

__global__ __launch_bounds__(256) void partial_kernel(
    const int* __restrict__ counts, int* __restrict__ blockSums) {
  __shared__ int s[256];
  const int t = threadIdx.x;
  const int idx = blockIdx.x * 256 + t;
  s[t] = (idx < N_NODES) ? counts[idx] : 0;
  __syncthreads();
  for (int off = 128; off > 0; off >>= 1) {
    if (t < off) s[t] += s[t + off];
    __syncthreads();
  }
  if (t == 0) blockSums[blockIdx.x] = s[0];
}

__global__ __launch_bounds__(512) void scan_blk_kernel(
    const int* __restrict__ blockSums, int* __restrict__ blockOff,
    int* __restrict__ row_ptr) {
  __shared__ int s[512];
  const int t = threadIdx.x;
  int v = (t < SCAN_BLK) ? blockSums[t] : 0;
  s[t] = v;
  __syncthreads();
  for (int off = 1; off < 512; off <<= 1) {
    int u = (t >= off) ? s[t - off] : 0;
    __syncthreads();
    s[t] += u;
    __syncthreads();
  }
  if (t < SCAN_BLK) blockOff[t] = s[t] - v;
  if (t == 511) row_ptr[N_NODES] = s[511];
}

__global__ __launch_bounds__(256) void scan_fin_kernel(
    const int* __restrict__ counts, const int* __restrict__ blockOff,
    int* __restrict__ row_ptr, int* __restrict__ cursor) {
  __shared__ int s[256];
  const int t = threadIdx.x;
  const int idx = blockIdx.x * 256 + t;
  const int v = (idx < N_NODES) ? counts[idx] : 0;
  s[t] = v;
  __syncthreads();
  for (int off = 1; off < 256; off <<= 1) {
    int u = (t >= off) ? s[t - off] : 0;
    __syncthreads();
    s[t] += u;
    __syncthreads();
  }
  if (idx < N_NODES) {
    int excl = s[t] - v + blockOff[blockIdx.x];
    row_ptr[idx] = excl;
    cursor[idx] = excl;
  }
}

__global__ __launch_bounds__(256) void fill_kernel(
    const int* __restrict__ ei, const float* __restrict__ attr,
    int* __restrict__ cursor, int2* __restrict__ csr) {
  int e = blockIdx.x * blockDim.x + threadIdx.x;
  if (e >= N_EDGES) return;
  int s = ei[e];
  int d = ei[N_EDGES + e];
  int pos = atomicAdd(cursor + d, 1);
  csr[pos] = make_int2(s, __float_as_int(attr[e]));
}

// ---------------------------------------------------------------------------
// Gather aggregation: one wave per node, float2 per lane.
// ---------------------------------------------------------------------------
__global__ __launch_bounds__(256) void gather_kernel(
    const float* __restrict__ x, const int* __restrict__ row_ptr,
    const int2* __restrict__ csr, float* __restrict__ out) {
  const int node = blockIdx.x * 4 + (threadIdx.x >> 6);
  const int lane = threadIdx.x & 63;
  if (node >= N_NODES) return;

  const int beg = row_ptr[node];
  const int end = row_ptr[node + 1];

  float2 acc = make_float2(0.f, 0.f);
  int e = beg;
  for (; e + 3 < end; e += 4) {
    int2 e0 = csr[e];
    int2 e1 = csr[e + 1];
    int2 e2 = csr[e + 2];
    int2 e3 = csr[e + 3];
    float2 v0 = *(const float2*)(x + (size_t)e0.x * DIM + lane * 2);
    float2 v1 = *(const float2*)(x + (size_t)e1.x * DIM + lane * 2);
    float2 v2 = *(const float2*)(x + (size_t)e2.x * DIM + lane * 2);
    float2 v3 = *(const float2*)(x + (size_t)e3.x * DIM + lane * 2);
    float a0 = __int_as_float(e0.y), a1 = __int_as_float(e1.y);
    float a2 = __int_as_float(e2.y), a3 = __int_as_float(e3.y);
    acc.x += v0.x * a0; acc.y += v0.y * a0;
    acc.x += v1.x * a1; acc.y += v1.y * a1;
    acc.x += v2.x * a2; acc.y += v2.y * a2;
    acc.x += v3.x * a3; acc.y += v3.y * a3;
  }
  for (; e < end; ++e) {
    int2 e0 = csr[e];
    float a0 = __int_as_float(e0.y);
    float2 v0 = *(const float2*)(x + (size_t)e0.x * DIM + lane * 2);
    acc.x += v0.x * a0; acc.y += v0.y * a0;
  }
  *(float2*)(out + (size_t)node * DIM + lane * 2) = acc;
}

// ---------------------------------------------------------------------------
// Pre-kernel: materialize W^T in MFMA B-fragment lane order, bf16.
// Layout: wfrag[(nt*4+q)*64 + lane] = 8 bf16 = W[n][k..k+8),
//   n = nt*16 + (lane&15), k = q*32 + (lane>>4)*8.
// 8 blocks x 256 threads = 2048 = 8 nt * 4 q * 64 lanes.
// ---------------------------------------------------------------------------
__global__ __launch_bounds__(256) void w_frag_kernel(
    const float* __restrict__ W, bf16x8* __restrict__ wfrag) {
  const int gid = blockIdx.x * 256 + threadIdx.x;  // 0..2047
  const int lane = gid & 63;
  const int q = (gid >> 6) & 3;
  const int nt = gid >> 8;
  const int n = nt * 16 + (lane & 15);
  const int kb = q * 32 + ((lane >> 4) & 3) * 8;
  const float4 f0 = *(const float4*)(W + n * DIM + kb);
  const float4 f1 = *(const float4*)(W + n * DIM + kb + 4);
  bf16x8 frag;
  frag[0] = (short)f2bf(f0.x); frag[1] = (short)f2bf(f0.y);
  frag[2] = (short)f2bf(f0.z); frag[3] = (short)f2bf(f0.w);
  frag[4] = (short)f2bf(f1.x); frag[5] = (short)f2bf(f1.y);
  frag[6] = (short)f2bf(f1.z); frag[7] = (short)f2bf(f1.w);
  wfrag[gid] = frag;
}

// ---------------------------------------------------------------------------
// MFMA linear: out = LeakyReLU(agg @ W^T + b), in-place safe (agg == out ok:
// each 16-row tile is loaded and stored by exactly one wave, loads precede
// stores in wave program order).
// Block = 256 threads = 4 waves; wave = 16 rows x 128 cols (32 MFMAs, K=128).
// No LDS. B-fragments are pre-laned in ws (L2-resident, coalesced dwordx4).
// ---------------------------------------------------------------------------
__global__ __launch_bounds__(256) void linear_mfma_kernel(
    const float* __restrict__ agg, const bf16x8* __restrict__ wfrag,
    const float* __restrict__ bias, float* __restrict__ out) {
  const int wave = threadIdx.x >> 6;
  const int lane = threadIdx.x & 63;
  const int r0 = (blockIdx.x * 4 + wave) * 16;
  if (r0 >= N_NODES) return;

  const int m = lane & 15;
  const int quad = lane >> 4;  // 0..3
  const int row = r0 + m;

  // A fragments: 4 k-steps, 8 consecutive fp32 each -> bf16x8
  bf16x8 afrag[4];
#pragma unroll
  for (int q = 0; q < 4; ++q) {
    const float* ap = agg + (size_t)row * DIM + q * 32 + quad * 8;
    const float4 f0 = *(const float4*)(ap);
    const float4 f1 = *(const float4*)(ap + 4);
    afrag[q][0] = (short)f2bf(f0.x); afrag[q][1] = (short)f2bf(f0.y);
    afrag[q][2] = (short)f2bf(f0.z); afrag[q][3] = (short)f2bf(f0.w);
    afrag[q][4] = (short)f2bf(f1.x); afrag[q][5] = (short)f2bf(f1.y);
    afrag[q][6] = (short)f2bf(f1.z); afrag[q][7] = (short)f2bf(f1.w);
  }

#pragma unroll
  for (int nt = 0; nt < 8; ++nt) {
    const float bv = bias[nt * 16 + m];
    f32x4 acc = {bv, bv, bv, bv};
#pragma unroll
    for (int q = 0; q < 4; ++q) {
      bf16x8 bfrag = wfrag[(nt * 4 + q) * 64 + lane];
      acc = __builtin_amdgcn_mfma_f32_16x16x32_bf16(afrag[q], bfrag, acc, 0, 0, 0);
    }
    // C/D layout: col = lane&15, row = quad*4 + reg
    const int col = nt * 16 + m;
#pragma unroll
    for (int i = 0; i < 4; ++i) {
      float v = acc[i];
      v = v >= 0.f ? v : v * LEAKY;
      out[(size_t)(r0 + quad * 4 + i) * DIM + col] = v;
    }
  }
}

// ---------------------------------------------------------------------------
// Fallback path kernels (ws too small): atomic scatter + LDS vector linear.
// ---------------------------------------------------------------------------
__global__ __launch_bounds__(256) void scatter_kernel(
    const float* __restrict__ x, const int* __restrict__ ei,
    const float* __restrict__ attr, float* __restrict__ agg) {
  int gid = blockIdx.x * blockDim.x + threadIdx.x;
  int e = gid >> 5;
  int f = (gid & 31) * 4;
  if (e >= N_EDGES) return;
  int s = ei[e];
  int d = ei[N_EDGES + e];
  float a = attr[e];
  const float4 xv = *(const float4*)(x + (size_t)s * DIM + f);
  float* dp = agg + (size_t)d * DIM + f;
  atomicAdd(dp + 0, xv.x * a);
  atomicAdd(dp + 1, xv.y * a);
  atomicAdd(dp + 2, xv.z * a);
  atomicAdd(dp + 3, xv.w * a);
}

__global__ __launch_bounds__(256, 2) void linear_kernel(
    const float* __restrict__ agg, const float* __restrict__ W,
    const float* __restrict__ bias, float* __restrict__ out) {
  __shared__ float Rs[32 * RS_STRIDE];
  __shared__ float Ws[64 * WS_STRIDE];

  const int tid = threadIdx.x;
  const int c = (tid & 31) * 4;
  const int rg = tid >> 5;
  const size_t rowBase = (size_t)blockIdx.x * 32;

  {
    const int lr = tid >> 3;
    const int col = (tid & 7) * 16;
    const float4* src = (const float4*)(agg + (rowBase + lr) * DIM + col);
#pragma unroll
    for (int j = 0; j < 4; ++j) {
      *(float4*)(Rs + lr * RS_STRIDE + col + j * 4) = src[j];
    }
  }

  const float4 bv = *(const float4*)(bias + c);
  float4 acc0 = bv, acc1 = bv, acc2 = bv, acc3 = bv;

  for (int half = 0; half < 2; ++half) {
    __syncthreads();
    {
      const int k0 = tid >> 7;
      const int o = tid & 127;
#pragma unroll
      for (int kk = k0; kk < 64; kk += 2) {
        Ws[kk * WS_STRIDE + o] = W[o * DIM + half * 64 + kk];
      }
    }
    __syncthreads();

    const float* rs0 = Rs + (rg * 4 + 0) * RS_STRIDE + half * 64;
    const float* rs1 = Rs + (rg * 4 + 1) * RS_STRIDE + half * 64;
    const float* rs2 = Rs + (rg * 4 + 2) * RS_STRIDE + half * 64;
    const float* rs3 = Rs + (rg * 4 + 3) * RS_STRIDE + half * 64;

#pragma unroll 8
    for (int k4 = 0; k4 < 16; ++k4) {
      const float4 v0 = *(const float4*)(rs0 + k4 * 4);
      const float4 v1 = *(const float4*)(rs1 + k4 * 4);
      const float4 v2 = *(const float4*)(rs2 + k4 * 4);
      const float4 v3 = *(const float4*)(rs3 + k4 * 4);
      const float4 w0 = *(const float4*)(Ws + (k4 * 4 + 0) * WS_STRIDE + c);
      const float4 w1 = *(const float4*)(Ws + (k4 * 4 + 1) * WS_STRIDE + c);
      const float4 w2 = *(const float4*)(Ws + (k4 * 4 + 2) * WS_STRIDE + c);
      const float4 w3 = *(const float4*)(Ws + (k4 * 4 + 3) * WS_STRIDE + c);

#define FMA4(acc, v)                                               \
      acc.x += v.x * w0.x + v.y * w1.x + v.z * w2.x + v.w * w3.x;  \
      acc.y += v.x * w0.y + v.y * w1.y + v.z * w2.y + v.w * w3.y;  \
      acc.z += v.x * w0.z + v.y * w1.z + v.z * w2.z + v.w * w3.z;  \
      acc.w += v.x * w0.w + v.y * w1.w + v.z * w2.w + v.w * w3.w;
      FMA4(acc0, v0)
      FMA4(acc1, v1)
      FMA4(acc2, v2)
      FMA4(acc3, v3)
#undef FMA4
    }
  }

#define LEAKY4(acc)                                   \
  acc.x = acc.x >= 0.f ? acc.x : acc.x * LEAKY;       \
  acc.y = acc.y >= 0.f ? acc.y : acc.y * LEAKY;       \
  acc.z = acc.z >= 0.f ? acc.z : acc.z * LEAKY;       \
  acc.w = acc.w >= 0.f ? acc.w : acc.w * LEAKY;
  LEAKY4(acc0) LEAKY4(acc1) LEAKY4(acc2) LEAKY4(acc3)
#undef LEAKY4

  const int row0 = (int)rowBase + rg * 4;
  *(float4*)(out + (size_t)(row0 + 0) * DIM + c) = acc0;
  *(float4*)(out + (size_t)(row0 + 1) * DIM + c) = acc1;
  *(float4*)(out + (size_t)(row0 + 2) * DIM + c) = acc2;
  *(float4*)(out + (size_t)(row0 + 3) * DIM + c) = acc3;
}

extern "C" void kernel_launch(void* const* d_in, const int* in_sizes, int n_in,
                              void* d_out, int out_size, void* d_ws, size_t ws_size,
                              hipStream_t stream) {
  const float* x = (const float*)d_in[0];
  const int* ei = (const int*)d_in[1];  // int32 (harness converts int64)
  const float* attr = (const float*)d_in[2];
  const float* W = (const float*)d_in[3];
  const float* b = (const float*)d_in[4];
  float* out = (float*)d_out;

  // Workspace layout (256B-aligned offsets)
  const size_t offCounts = 0;                        // N ints
  const size_t offRowPtr = 400128;                   // N+1 ints
  const size_t offCursor = 800256;                   // N ints
  const size_t offCsr = 1200384;                     // E int2
  const size_t offBs = offCsr + (size_t)N_EDGES * 8; // 391 ints
  const size_t offBo = offBs + 1792;                 // 391 ints
  const size_t offWf = offBo + 2048;                 // 2048 * 16B = 32KB
  const size_t wsNeeded = offWf + 32768;             // ~14.04 MB

  if (ws_size >= wsNeeded) {
    char* ws = (char*)d_ws;
    int* counts = (int*)(ws + offCounts);
    int* row_ptr = (int*)(ws + offRowPtr);
    int* cursor = (int*)(ws + offCursor);
    int2* csr = (int2*)(ws + offCsr);
    int* blockSums = (int*)(ws + offBs);
    int* blockOff = (int*)(ws + offBo);
    bf16x8* wfrag = (bf16x8*)(ws + offWf);

    hipMemsetAsync(counts, 0, (size_t)N_NODES * sizeof(int), stream);
    w_frag_kernel<<<8, 256, 0, stream>>>(W, wfrag);
    hist_kernel<<<(N_EDGES + 255) / 256, 256, 0, stream>>>(ei, counts);
    partial_kernel<<<SCAN_BLK, 256, 0, stream>>>(counts, blockSums);
    scan_blk_kernel<<<1, 512, 0, stream>>>(blockSums, blockOff, row_ptr);
    scan_fin_kernel<<<SCAN_BLK, 256, 0, stream>>>(counts, blockOff, row_ptr, cursor);
    fill_kernel<<<(N_EDGES + 255) / 256, 256, 0, stream>>>(ei, attr, cursor, csr);
    gather_kernel<<<(N_NODES + 3) / 4, 256, 0, stream>>>(x, row_ptr, csr, out);
    linear_mfma_kernel<<<(N_NODES + 63) / 64, 256, 0, stream>>>(out, wfrag, b, out);
  } else {
    hipMemsetAsync(out, 0, (size_t)N_NODES * DIM * sizeof(float), stream);
    scatter_kernel<<<(N_EDGES * 32) / 256, 256, 0, stream>>>(x, ei, attr, out);
    linear_kernel<<<N_NODES / 32, 256, 0, stream>>>(out, W, b, out);
  }
}

// Round 6
// 250.477 us; speedup vs baseline: 11.4965x; 1.6694x over previous
//
#include <hip/hip_runtime.h>

#define N_NODES 100000
#define N_EDGES 1600000
#define DIM 128
#define LEAKY 0.01f
#define RS_STRIDE 132
#define WS_STRIDE 132
#define NBUCKET 391      // ceil(100000/256) nodes-per-bucket buckets (d>>8)
#define SB_EDGES 4096    // edges per sort_local block
#define NSB 391          // ceil(1600000/4096)

typedef short bf16x8 __attribute__((ext_vector_type(8)));
typedef float f32x4 __attribute__((ext_vector_type(4)));

static __device__ __forceinline__ unsigned short f2bf(float f) {
  unsigned int u = __float_as_uint(f);
  u = (u + 0x7fffu + ((u >> 16) & 1u)) >> 16;  // RNE
  return (unsigned short)u;
}

// ---------------------------------------------------------------------------
// K1: local bucket sort. Each block takes 4096 edges, histograms bucket
// (= dst>>8, 391 buckets), scans in LDS, stages sorted-by-bucket records in
// LDS, writes them out fully coalesced. Record: {src | localD<<17, attr}.
// Also emits counts[b][sb] (ushort) and srcOff[b][sb] (run start in binned).
// ---------------------------------------------------------------------------
__global__ __launch_bounds__(512) void sort_local_kernel(
    const int* __restrict__ ei, const float* __restrict__ attr,
    int2* __restrict__ binned, unsigned short* __restrict__ counts,
    int* __restrict__ srcOff) {
  __shared__ int hist[NBUCKET];
  __shared__ int cursor[NBUCKET];
  __shared__ int scanBuf[512];
  __shared__ int2 stage[SB_EDGES];  // 32 KB

  const int t = threadIdx.x;
  const int blk = blockIdx.x;
  const int base = blk * SB_EDGES;
  const int n = min(SB_EDGES, N_EDGES - base);

  if (t < NBUCKET) hist[t] = 0;
  __syncthreads();

  int myP[8];   // packed src|localD<<17, or -1 sentinel bucket
  int myB[8];
  float myA[8];
#pragma unroll
  for (int k = 0; k < 8; ++k) {
    int i = t + k * 512;
    if (i < n) {
      int e = base + i;
      int s = ei[e];
      int d = ei[N_EDGES + e];
      myA[k] = attr[e];
      myB[k] = d >> 8;
      myP[k] = s | ((d & 255) << 17);
      atomicAdd(&hist[myB[k]], 1);
    } else {
      myB[k] = -1;
    }
  }
  __syncthreads();

  // exclusive scan of hist (Hillis-Steele over 512)
  int v = (t < NBUCKET) ? hist[t] : 0;
  scanBuf[t] = v;
  __syncthreads();
  for (int off = 1; off < 512; off <<= 1) {
    int u = (t >= off) ? scanBuf[t - off] : 0;
    __syncthreads();
    scanBuf[t] += u;
    __syncthreads();
  }
  if (t < NBUCKET) {
    int excl = scanBuf[t] - v;
    cursor[t] = excl;
    counts[(size_t)t * NSB + blk] = (unsigned short)v;
    srcOff[(size_t)t * NSB + blk] = base + excl;
  }
  __syncthreads();

#pragma unroll
  for (int k = 0; k < 8; ++k) {
    if (myB[k] >= 0) {
      int loc = atomicAdd(&cursor[myB[k]], 1);
      stage[loc] = make_int2(myP[k], __float_as_int(myA[k]));
    }
  }
  __syncthreads();

  for (int i = t; i < n; i += 512) binned[base + i] = stage[i];
}

// ---------------------------------------------------------------------------
// K2a: bucketCount[b] = sum_sb counts[b][sb]
// ---------------------------------------------------------------------------
__global__ __launch_bounds__(128) void bucket_count_kernel(
    const unsigned short* __restrict__ counts, int* __restrict__ bucketCount) {
  __shared__ int red[128];
  const int b = blockIdx.x;
  const int t = threadIdx.x;
  int s = 0;
  for (int sb = t; sb < NSB; sb += 128) s += counts[(size_t)b * NSB + sb];
  red[t] = s;
  __syncthreads();
  for (int off = 64; off > 0; off >>= 1) {
    if (t < off) red[t] += red[t + off];
    __syncthreads();
  }
  if (t == 0) bucketCount[b] = red[0];
}

// ---------------------------------------------------------------------------
// K2b: exclusive scan of 391 bucket counts -> bucketBase
// ---------------------------------------------------------------------------
__global__ __launch_bounds__(512) void bucket_scan_kernel(
    const int* __restrict__ bucketCount, int* __restrict__ bucketBase) {
  __shared__ int s[512];
  const int t = threadIdx.x;
  int v = (t < NBUCKET) ? bucketCount[t] : 0;
  s[t] = v;
  __syncthreads();
  for (int off = 1; off < 512; off <<= 1) {
    int u = (t >= off) ? s[t - off] : 0;
    __syncthreads();
    s[t] += u;
    __syncthreads();
  }
  if (t < NBUCKET) bucketBase[t] = s[t] - v;
}

// ---------------------------------------------------------------------------
// K3: per-bucket counting sort -> csr + row_ptr. One block per bucket
// (256 nodes). Two passes over the bucket's 391 runs (count, then place),
// so no LDS edge staging and no capacity limit. All csr writes for a bucket
// come from ONE block (one XCD) -> single clean writeback per line.
// ---------------------------------------------------------------------------
__global__ __launch_bounds__(512) void passB_kernel(
    const int2* __restrict__ binned, const unsigned short* __restrict__ counts,
    const int* __restrict__ srcOff, const int* __restrict__ bucketBase,
    int2* __restrict__ csr, int* __restrict__ row_ptr) {
  __shared__ int runPrefix[NSB + 1];
  __shared__ int runSrc[NSB];
  __shared__ int hist[256];
  __shared__ int nodeBase[256];
  __shared__ int cur[256];
  __shared__ int scanBuf[512];

  const int b = blockIdx.x;
  const int t = threadIdx.x;

  if (t < NSB) runSrc[t] = srcOff[(size_t)b * NSB + t];
  int len = (t < NSB) ? (int)counts[(size_t)b * NSB + t] : 0;
  scanBuf[t] = len;
  __syncthreads();
  for (int off = 1; off < 512; off <<= 1) {
    int u = (t >= off) ? scanBuf[t - off] : 0;
    __syncthreads();
    scanBuf[t] += u;
    __syncthreads();
  }
  if (t < NSB) runPrefix[t] = scanBuf[t] - len;
  if (t == NSB) runPrefix[NSB] = scanBuf[NSB];  // == total (lens beyond are 0)
  if (t < 256) hist[t] = 0;
  __syncthreads();

  const int total = runPrefix[NSB];

  // pass 1: per-node histogram
  for (int i = t; i < total; i += 512) {
    int lo = 0, hi = NSB - 1;
    while (lo < hi) {
      int mid = (lo + hi + 1) >> 1;
      if (runPrefix[mid] <= i) lo = mid; else hi = mid - 1;
    }
    int px = binned[runSrc[lo] + (i - runPrefix[lo])].x;
    atomicAdd(&hist[(px >> 17) & 255], 1);
  }
  __syncthreads();

  // scan hist -> nodeBase (exclusive), cursor copy
  int hv = (t < 256) ? hist[t] : 0;
  scanBuf[t] = hv;
  __syncthreads();
  for (int off = 1; off < 512; off <<= 1) {
    int u = (t >= off) ? scanBuf[t - off] : 0;
    __syncthreads();
    scanBuf[t] += u;
    __syncthreads();
  }
  const int bb = bucketBase[b];
  if (t < 256) {
    int excl = scanBuf[t] - hv;
    nodeBase[t] = excl;
    cur[t] = excl;
    int node = b * 256 + t;
    if (node < N_NODES) row_ptr[node] = bb + excl;
  }
  if (b == 0 && t == 0) row_ptr[N_NODES] = N_EDGES;
  __syncthreads();

  // pass 2: place records
  for (int i = t; i < total; i += 512) {
    int lo = 0, hi = NSB - 1;
    while (lo < hi) {
      int mid = (lo + hi + 1) >> 1;
      if (runPrefix[mid] <= i) lo = mid; else hi = mid - 1;
    }
    int2 rec = binned[runSrc[lo] + (i - runPrefix[lo])];
    int ld = (rec.x >> 17) & 255;
    int pos = bb + atomicAdd(&cur[ld], 1);
    csr[pos] = make_int2(rec.x & 0x1FFFF, rec.y);
  }
}

// ---------------------------------------------------------------------------
// x -> bf16 conversion (one float4 -> one ushort4 per thread)
// ---------------------------------------------------------------------------
__global__ __launch_bounds__(256) void x2b_kernel(
    const float4* __restrict__ x, ushort4* __restrict__ xb) {
  const int i = blockIdx.x * 256 + threadIdx.x;  // 3.2M exactly
  float4 v = x[i];
  ushort4 o;
  o.x = f2bf(v.x); o.y = f2bf(v.y); o.z = f2bf(v.z); o.w = f2bf(v.w);
  xb[i] = o;
}

// ---------------------------------------------------------------------------
// Gather aggregation (bf16 x): one wave per node, 2 feats per lane.
// ---------------------------------------------------------------------------
__global__ __launch_bounds__(256) void gather_bf16_kernel(
    const unsigned short* __restrict__ xb, const int* __restrict__ row_ptr,
    const int2* __restrict__ csr, float* __restrict__ out) {
  const int node = blockIdx.x * 4 + (threadIdx.x >> 6);
  const int lane = threadIdx.x & 63;

  const int beg = row_ptr[node];
  const int end = row_ptr[node + 1];

  float2 acc = make_float2(0.f, 0.f);
  int e = beg;
  for (; e + 3 < end; e += 4) {
    int2 e0 = csr[e];
    int2 e1 = csr[e + 1];
    int2 e2 = csr[e + 2];
    int2 e3 = csr[e + 3];
    unsigned int u0 = *(const unsigned int*)(xb + (size_t)e0.x * DIM + lane * 2);
    unsigned int u1 = *(const unsigned int*)(xb + (size_t)e1.x * DIM + lane * 2);
    unsigned int u2 = *(const unsigned int*)(xb + (size_t)e2.x * DIM + lane * 2);
    unsigned int u3 = *(const unsigned int*)(xb + (size_t)e3.x * DIM + lane * 2);
    float a0 = __int_as_float(e0.y), a1 = __int_as_float(e1.y);
    float a2 = __int_as_float(e2.y), a3 = __int_as_float(e3.y);
    acc.x += __uint_as_float(u0 << 16) * a0;
    acc.y += __uint_as_float(u0 & 0xffff0000u) * a0;
    acc.x += __uint_as_float(u1 << 16) * a1;
    acc.y += __uint_as_float(u1 & 0xffff0000u) * a1;
    acc.x += __uint_as_float(u2 << 16) * a2;
    acc.y += __uint_as_float(u2 & 0xffff0000u) * a2;
    acc.x += __uint_as_float(u3 << 16) * a3;
    acc.y += __uint_as_float(u3 & 0xffff0000u) * a3;
  }
  for (; e < end; ++e) {
    int2 e0 = csr[e];
    float a0 = __int_as_float(e0.y);
    unsigned int u0 = *(const unsigned int*)(xb + (size_t)e0.x * DIM + lane * 2);
    acc.x += __uint_as_float(u0 << 16) * a0;
    acc.y += __uint_as_float(u0 & 0xffff0000u) * a0;
  }
  *(float2*)(out + (size_t)node * DIM + lane * 2) = acc;
}

// fp32-x gather (used when ws can't hold xb)
__global__ __launch_bounds__(256) void gather_f32_kernel(
    const float* __restrict__ x, const int* __restrict__ row_ptr,
    const int2* __restrict__ csr, float* __restrict__ out) {
  const int node = blockIdx.x * 4 + (threadIdx.x >> 6);
  const int lane = threadIdx.x & 63;

  const int beg = row_ptr[node];
  const int end = row_ptr[node + 1];

  float2 acc = make_float2(0.f, 0.f);
  int e = beg;
  for (; e + 3 < end; e += 4) {
    int2 e0 = csr[e];
    int2 e1 = csr[e + 1];
    int2 e2 = csr[e + 2];
    int2 e3 = csr[e + 3];
    float2 v0 = *(const float2*)(x + (size_t)e0.x * DIM + lane * 2);
    float2 v1 = *(const float2*)(x + (size_t)e1.x * DIM + lane * 2);
    float2 v2 = *(const float2*)(x + (size_t)e2.x * DIM + lane * 2);
    float2 v3 = *(const float2*)(x + (size_t)e3.x * DIM + lane * 2);
    float a0 = __int_as_float(e0.y), a1 = __int_as_float(e1.y);
    float a2 = __int_as_float(e2.y), a3 = __int_as_float(e3.y);
    acc.x += v0.x * a0; acc.y += v0.y * a0;
    acc.x += v1.x * a1; acc.y += v1.y * a1;
    acc.x += v2.x * a2; acc.y += v2.y * a2;
    acc.x += v3.x * a3; acc.y += v3.y * a3;
  }
  for (; e < end; ++e) {
    int2 e0 = csr[e];
    float a0 = __int_as_float(e0.y);
    float2 v0 = *(const float2*)(x + (size_t)e0.x * DIM + lane * 2);
    acc.x += v0.x * a0; acc.y += v0.y * a0;
  }
  *(float2*)(out + (size_t)node * DIM + lane * 2) = acc;
}

// ---------------------------------------------------------------------------
// W^T -> MFMA B-fragments (bf16, lane order), 8 blocks x 256.
// ---------------------------------------------------------------------------
__global__ __launch_bounds__(256) void w_frag_kernel(
    const float* __restrict__ W, bf16x8* __restrict__ wfrag) {
  const int gid = blockIdx.x * 256 + threadIdx.x;  // 0..2047
  const int lane = gid & 63;
  const int q = (gid >> 6) & 3;
  const int nt = gid >> 8;
  const int n = nt * 16 + (lane & 15);
  const int kb = q * 32 + ((lane >> 4) & 3) * 8;
  const float4 f0 = *(const float4*)(W + n * DIM + kb);
  const float4 f1 = *(const float4*)(W + n * DIM + kb + 4);
  bf16x8 frag;
  frag[0] = (short)f2bf(f0.x); frag[1] = (short)f2bf(f0.y);
  frag[2] = (short)f2bf(f0.z); frag[3] = (short)f2bf(f0.w);
  frag[4] = (short)f2bf(f1.x); frag[5] = (short)f2bf(f1.y);
  frag[6] = (short)f2bf(f1.z); frag[7] = (short)f2bf(f1.w);
  wfrag[gid] = frag;
}

// ---------------------------------------------------------------------------
// MFMA linear: out = LeakyReLU(agg @ W^T + b), in-place safe.
// ---------------------------------------------------------------------------
__global__ __launch_bounds__(256) void linear_mfma_kernel(
    const float* __restrict__ agg, const bf16x8* __restrict__ wfrag,
    const float* __restrict__ bias, float* __restrict__ out) {
  const int wave = threadIdx.x >> 6;
  const int lane = threadIdx.x & 63;
  const int r0 = (blockIdx.x * 4 + wave) * 16;
  if (r0 >= N_NODES) return;

  const int m = lane & 15;
  const int quad = lane >> 4;
  const int row = r0 + m;

  bf16x8 afrag[4];
#pragma unroll
  for (int q = 0; q < 4; ++q) {
    const float* ap = agg + (size_t)row * DIM + q * 32 + quad * 8;
    const float4 f0 = *(const float4*)(ap);
    const float4 f1 = *(const float4*)(ap + 4);
    afrag[q][0] = (short)f2bf(f0.x); afrag[q][1] = (short)f2bf(f0.y);
    afrag[q][2] = (short)f2bf(f0.z); afrag[q][3] = (short)f2bf(f0.w);
    afrag[q][4] = (short)f2bf(f1.x); afrag[q][5] = (short)f2bf(f1.y);
    afrag[q][6] = (short)f2bf(f1.z); afrag[q][7] = (short)f2bf(f1.w);
  }

#pragma unroll
  for (int nt = 0; nt < 8; ++nt) {
    const float bv = bias[nt * 16 + m];
    f32x4 acc = {bv, bv, bv, bv};
#pragma unroll
    for (int q = 0; q < 4; ++q) {
      bf16x8 bfrag = wfrag[(nt * 4 + q) * 64 + lane];
      acc = __builtin_amdgcn_mfma_f32_16x16x32_bf16(afrag[q], bfrag, acc, 0, 0, 0);
    }
    const int col = nt * 16 + m;
#pragma unroll
    for (int i = 0; i < 4; ++i) {
      float v = acc[i];
      v = v >= 0.f ? v : v * LEAKY;
      out[(size_t)(r0 + quad * 4 + i) * DIM + col] = v;
    }
  }
}

// ---------------------------------------------------------------------------
// Fallback path (tiny ws): atomic scatter + LDS vector linear.
// ---------------------------------------------------------------------------
__global__ __launch_bounds__(256) void scatter_kernel(
    const float* __restrict__ x, const int* __restrict__ ei,
    const float* __restrict__ attr, float* __restrict__ agg) {
  int gid = blockIdx.x * blockDim.x + threadIdx.x;
  int e = gid >> 5;
  int f = (gid & 31) * 4;
  if (e >= N_EDGES) return;
  int s = ei[e];
  int d = ei[N_EDGES + e];
  float a = attr[e];
  const float4 xv = *(const float4*)(x + (size_t)s * DIM + f);
  float* dp = agg + (size_t)d * DIM + f;
  atomicAdd(dp + 0, xv.x * a);
  atomicAdd(dp + 1, xv.y * a);
  atomicAdd(dp + 2, xv.z * a);
  atomicAdd(dp + 3, xv.w * a);
}

__global__ __launch_bounds__(256, 2) void linear_kernel(
    const float* __restrict__ agg, const float* __restrict__ W,
    const float* __restrict__ bias, float* __restrict__ out) {
  __shared__ float Rs[32 * RS_STRIDE];
  __shared__ float Ws[64 * WS_STRIDE];

  const int tid = threadIdx.x;
  const int c = (tid & 31) * 4;
  const int rg = tid >> 5;
  const size_t rowBase = (size_t)blockIdx.x * 32;

  {
    const int lr = tid >> 3;
    const int col = (tid & 7) * 16;
    const float4* src = (const float4*)(agg + (rowBase + lr) * DIM + col);
#pragma unroll
    for (int j = 0; j < 4; ++j) {
      *(float4*)(Rs + lr * RS_STRIDE + col + j * 4) = src[j];
    }
  }

  const float4 bv = *(const float4*)(bias + c);
  float4 acc0 = bv, acc1 = bv, acc2 = bv, acc3 = bv;

  for (int half = 0; half < 2; ++half) {
    __syncthreads();
    {
      const int k0 = tid >> 7;
      const int o = tid & 127;
#pragma unroll
      for (int kk = k0; kk < 64; kk += 2) {
        Ws[kk * WS_STRIDE + o] = W[o * DIM + half * 64 + kk];
      }
    }
    __syncthreads();

    const float* rs0 = Rs + (rg * 4 + 0) * RS_STRIDE + half * 64;
    const float* rs1 = Rs + (rg * 4 + 1) * RS_STRIDE + half * 64;
    const float* rs2 = Rs + (rg * 4 + 2) * RS_STRIDE + half * 64;
    const float* rs3 = Rs + (rg * 4 + 3) * RS_STRIDE + half * 64;

#pragma unroll 8
    for (int k4 = 0; k4 < 16; ++k4) {
      const float4 v0 = *(const float4*)(rs0 + k4 * 4);
      const float4 v1 = *(const float4*)(rs1 + k4 * 4);
      const float4 v2 = *(const float4*)(rs2 + k4 * 4);
      const float4 v3 = *(const float4*)(rs3 + k4 * 4);
      const float4 w0 = *(const float4*)(Ws + (k4 * 4 + 0) * WS_STRIDE + c);
      const float4 w1 = *(const float4*)(Ws + (k4 * 4 + 1) * WS_STRIDE + c);
      const float4 w2 = *(const float4*)(Ws + (k4 * 4 + 2) * WS_STRIDE + c);
      const float4 w3 = *(const float4*)(Ws + (k4 * 4 + 3) * WS_STRIDE + c);

#define FMA4(acc, v)                                               \
      acc.x += v.x * w0.x + v.y * w1.x + v.z * w2.x + v.w * w3.x;  \
      acc.y += v.x * w0.y + v.y * w1.y + v.z * w2.y + v.w * w3.y;  \
      acc.z += v.x * w0.z + v.y * w1.z + v.z * w2.z + v.w * w3.z;  \
      acc.w += v.x * w0.w + v.y * w1.w + v.z * w2.w + v.w * w3.w;
      FMA4(acc0, v0)
      FMA4(acc1, v1)
      FMA4(acc2, v2)
      FMA4(acc3, v3)
#undef FMA4
    }
  }

#define LEAKY4(acc)                                   \
  acc.x = acc.x >= 0.f ? acc.x : acc.x * LEAKY;       \
  acc.y = acc.y >= 0.f ? acc.y : acc.y * LEAKY;       \
  acc.z = acc.z >= 0.f ? acc.z : acc.z * LEAKY;       \
  acc.w = acc.w >= 0.f ? acc.w : acc.w * LEAKY;
  LEAKY4(acc0) LEAKY4(acc1) LEAKY4(acc2) LEAKY4(acc3)
#undef LEAKY4

  const int row0 = (int)rowBase + rg * 4;
  *(float4*)(out + (size_t)(row0 + 0) * DIM + c) = acc0;
  *(float4*)(out + (size_t)(row0 + 1) * DIM + c) = acc1;
  *(float4*)(out + (size_t)(row0 + 2) * DIM + c) = acc2;
  *(float4*)(out + (size_t)(row0 + 3) * DIM + c) = acc3;
}

extern "C" void kernel_launch(void* const* d_in, const int* in_sizes, int n_in,
                              void* d_out, int out_size, void* d_ws, size_t ws_size,
                              hipStream_t stream) {
  const float* x = (const float*)d_in[0];
  const int* ei = (const int*)d_in[1];  // int32
  const float* attr = (const float*)d_in[2];
  const float* W = (const float*)d_in[3];
  const float* b = (const float*)d_in[4];
  float* out = (float*)d_out;

  // Workspace layout
  const size_t offBinned = 0;                             // E int2
  const size_t offCounts = 12812288;                      // 391*391 ushort
  const size_t offSrcOff = offCounts + 305920;            // 391*391 int
  const size_t offBCount = offSrcOff + 611584;            // 391 int
  const size_t offBBase  = offBCount + 1792;              // 391 int
  const size_t offCsr    = offBBase + 1792;               // E int2
  const size_t offRowPtr = offCsr + 12812288;             // N+1 int
  const size_t offWfrag  = offRowPtr + 400128;            // 32 KB
  const size_t sortNeed  = offWfrag + 32768;              // ~27.0 MB
  const size_t offXb     = sortNeed;                      // N*DIM bf16
  const size_t fullNeed  = offXb + 25600000;              // ~52.6 MB

  if (ws_size >= sortNeed) {
    char* ws = (char*)d_ws;
    int2* binned = (int2*)(ws + offBinned);
    unsigned short* counts = (unsigned short*)(ws + offCounts);
    int* srcOff = (int*)(ws + offSrcOff);
    int* bucketCount = (int*)(ws + offBCount);
    int* bucketBase = (int*)(ws + offBBase);
    int2* csr = (int2*)(ws + offCsr);
    int* row_ptr = (int*)(ws + offRowPtr);
    bf16x8* wfrag = (bf16x8*)(ws + offWfrag);

    w_frag_kernel<<<8, 256, 0, stream>>>(W, wfrag);
    sort_local_kernel<<<NSB, 512, 0, stream>>>(ei, attr, binned, counts, srcOff);
    bucket_count_kernel<<<NBUCKET, 128, 0, stream>>>(counts, bucketCount);
    bucket_scan_kernel<<<1, 512, 0, stream>>>(bucketCount, bucketBase);
    passB_kernel<<<NBUCKET, 512, 0, stream>>>(binned, counts, srcOff, bucketBase,
                                              csr, row_ptr);
    if (ws_size >= fullNeed) {
      unsigned short* xb = (unsigned short*)(ws + offXb);
      x2b_kernel<<<12500, 256, 0, stream>>>((const float4*)x, (ushort4*)xb);
      gather_bf16_kernel<<<N_NODES / 4, 256, 0, stream>>>(xb, row_ptr, csr, out);
    } else {
      gather_f32_kernel<<<N_NODES / 4, 256, 0, stream>>>(x, row_ptr, csr, out);
    }
    linear_mfma_kernel<<<(N_NODES + 63) / 64, 256, 0, stream>>>(out, wfrag, b, out);
  } else {
    hipMemsetAsync(out, 0, (size_t)N_NODES * DIM * sizeof(float), stream);
    scatter_kernel<<<(N_EDGES * 32) / 256, 256, 0, stream>>>(x, ei, attr, out);
    linear_kernel<<<N_NODES / 32, 256, 0, stream>>>(out, W, b, out);
  }
}